// Round 1
// baseline (125.719 us; speedup 1.0000x reference)
//
#include <hip/hip_runtime.h>

// SplineDisp: field[v] = ma @ (g(v) + cubic_bspline_pull(coeff, g(v))) where
// g(v) = fa @ v, fa = inv(affine)@fix_affine, ma = inv(mov_affine)@affine.
// Fixed problem size from setup_inputs: coeff [80,80,80,3] f32, out [160,160,160,3] f32.

#define CX 80
#define CC 3
#define FD 160
#define STRIDE_X (CX * CX * CC)  // 19200
#define STRIDE_Y (CX * CC)       // 240
#define STRIDE_Z (CC)            // 3

__device__ inline void inv4(const float* m, float* inv) {
    inv[0]  =  m[5]*m[10]*m[15] - m[5]*m[11]*m[14] - m[9]*m[6]*m[15] + m[9]*m[7]*m[14] + m[13]*m[6]*m[11] - m[13]*m[7]*m[10];
    inv[4]  = -m[4]*m[10]*m[15] + m[4]*m[11]*m[14] + m[8]*m[6]*m[15] - m[8]*m[7]*m[14] - m[12]*m[6]*m[11] + m[12]*m[7]*m[10];
    inv[8]  =  m[4]*m[9]*m[15]  - m[4]*m[11]*m[13] - m[8]*m[5]*m[15] + m[8]*m[7]*m[13] + m[12]*m[5]*m[11] - m[12]*m[7]*m[9];
    inv[12] = -m[4]*m[9]*m[14]  + m[4]*m[10]*m[13] + m[8]*m[5]*m[14] - m[8]*m[6]*m[13] - m[12]*m[5]*m[10] + m[12]*m[6]*m[9];
    inv[1]  = -m[1]*m[10]*m[15] + m[1]*m[11]*m[14] + m[9]*m[2]*m[15] - m[9]*m[3]*m[14] - m[13]*m[2]*m[11] + m[13]*m[3]*m[10];
    inv[5]  =  m[0]*m[10]*m[15] - m[0]*m[11]*m[14] - m[8]*m[2]*m[15] + m[8]*m[3]*m[14] + m[12]*m[2]*m[11] - m[12]*m[3]*m[10];
    inv[9]  = -m[0]*m[9]*m[15]  + m[0]*m[11]*m[13] + m[8]*m[1]*m[15] - m[8]*m[3]*m[13] - m[12]*m[1]*m[11] + m[12]*m[3]*m[9];
    inv[13] =  m[0]*m[9]*m[14]  - m[0]*m[10]*m[13] - m[8]*m[1]*m[14] + m[8]*m[2]*m[13] + m[12]*m[1]*m[10] - m[12]*m[2]*m[9];
    inv[2]  =  m[1]*m[6]*m[15]  - m[1]*m[7]*m[14]  - m[5]*m[2]*m[15] + m[5]*m[3]*m[14] + m[13]*m[2]*m[7]  - m[13]*m[3]*m[6];
    inv[6]  = -m[0]*m[6]*m[15]  + m[0]*m[7]*m[14]  + m[4]*m[2]*m[15] - m[4]*m[3]*m[14] - m[12]*m[2]*m[7]  + m[12]*m[3]*m[6];
    inv[10] =  m[0]*m[5]*m[15]  - m[0]*m[7]*m[13]  - m[4]*m[1]*m[15] + m[4]*m[3]*m[13] + m[12]*m[1]*m[7]  - m[12]*m[3]*m[5];
    inv[14] = -m[0]*m[5]*m[14]  + m[0]*m[6]*m[13]  + m[4]*m[1]*m[14] - m[4]*m[2]*m[13] - m[12]*m[1]*m[6]  + m[12]*m[2]*m[5];
    inv[3]  = -m[1]*m[6]*m[11]  + m[1]*m[7]*m[10]  + m[5]*m[2]*m[11] - m[5]*m[3]*m[10] - m[9]*m[2]*m[7]   + m[9]*m[3]*m[6];
    inv[7]  =  m[0]*m[6]*m[11]  - m[0]*m[7]*m[10]  - m[4]*m[2]*m[11] + m[4]*m[3]*m[10] + m[8]*m[2]*m[7]   - m[8]*m[3]*m[6];
    inv[11] = -m[0]*m[5]*m[11]  + m[0]*m[7]*m[9]   + m[4]*m[1]*m[11] - m[4]*m[3]*m[9]  - m[8]*m[1]*m[7]   + m[8]*m[3]*m[5];
    inv[15] =  m[0]*m[5]*m[10]  - m[0]*m[6]*m[9]   - m[4]*m[1]*m[10] + m[4]*m[2]*m[9]  + m[8]*m[1]*m[6]   - m[8]*m[2]*m[5];
    float det = m[0]*inv[0] + m[1]*inv[4] + m[2]*inv[8] + m[3]*inv[12];
    float rdet = 1.0f / det;
    for (int i = 0; i < 16; ++i) inv[i] *= rdet;
}

__global__ void setup_mats(const float* __restrict__ affine,
                           const float* __restrict__ fix_aff,
                           const float* __restrict__ mov_aff,
                           float* __restrict__ M) {
    if (threadIdx.x != 0 || blockIdx.x != 0) return;
    float invA[16], invM[16];
    inv4(affine, invA);
    inv4(mov_aff, invM);
    // fa = invA @ fix_aff   -> M[0..15]
    for (int r = 0; r < 4; ++r)
        for (int c = 0; c < 4; ++c) {
            float s = 0.f;
            for (int k = 0; k < 4; ++k) s += invA[r*4+k] * fix_aff[k*4+c];
            M[r*4+c] = s;
        }
    // ma = invM @ affine    -> M[16..31]
    for (int r = 0; r < 4; ++r)
        for (int c = 0; c < 4; ++c) {
            float s = 0.f;
            for (int k = 0; k < 4; ++k) s += invM[r*4+k] * affine[k*4+c];
            M[16 + r*4+c] = s;
        }
}

__device__ inline void bspline_w(float t, float w[4]) {
    float t2 = t * t;
    float t3 = t2 * t;
    const float s = 1.0f / 6.0f;
    w[0] = (1.f - 3.f*t + 3.f*t2 - t3) * s;
    w[1] = (4.f - 6.f*t2 + 3.f*t3) * s;
    w[2] = (1.f + 3.f*t + 3.f*t2 - 3.f*t3) * s;
    w[3] = t3 * s;
}

__device__ inline int wrap80(int v) {
    int r = v % CX;
    return (r < 0) ? r + CX : r;
}

__global__ __launch_bounds__(256) void spline_field(const float* __restrict__ coeff,
                                                    const float* __restrict__ M,
                                                    float* __restrict__ out) {
    int tid = blockIdx.x * 256 + threadIdx.x;
    // 160^3 = 4,096,000 = 16000 * 256 exactly; no tail.
    int k = tid % FD;
    int t2 = tid / FD;
    int j = t2 % FD;
    int i = t2 / FD;

    float fi = (float)i, fj = (float)j, fk = (float)k;
    float gx = M[0]*fi + M[1]*fj + M[2]*fk  + M[3];
    float gy = M[4]*fi + M[5]*fj + M[6]*fk  + M[7];
    float gz = M[8]*fi + M[9]*fj + M[10]*fk + M[11];

    float fx = floorf(gx), fy = floorf(gy), fz = floorf(gz);
    float tx = gx - fx, ty = gy - fy, tz = gz - fz;
    int bx = (int)fx - 1, by = (int)fy - 1, bz = (int)fz - 1;

    float wx[4], wy[4], wz[4];
    bspline_w(tx, wx);
    bspline_w(ty, wy);
    bspline_w(tz, wz);

    int ox[4], oy[4], oz[4];
#pragma unroll
    for (int a = 0; a < 4; ++a) {
        ox[a] = wrap80(bx + a) * STRIDE_X;
        oy[a] = wrap80(by + a) * STRIDE_Y;
        oz[a] = wrap80(bz + a) * STRIDE_Z;
    }

    float a0 = 0.f, a1 = 0.f, a2 = 0.f;
#pragma unroll
    for (int a = 0; a < 4; ++a) {
        float wa = wx[a];
        int oa = ox[a];
#pragma unroll
        for (int b = 0; b < 4; ++b) {
            float wab = wa * wy[b];
            int oab = oa + oy[b];
#pragma unroll
            for (int c = 0; c < 4; ++c) {
                float w = wab * wz[c];
                const float* p = coeff + (oab + oz[c]);
                a0 = fmaf(w, p[0], a0);
                a1 = fmaf(w, p[1], a1);
                a2 = fmaf(w, p[2], a2);
            }
        }
    }

    float ux = gx + a0, uy = gy + a1, uz = gz + a2;
    float o0 = M[16]*ux + M[17]*uy + M[18]*uz + M[19];
    float o1 = M[20]*ux + M[21]*uy + M[22]*uz + M[23];
    float o2 = M[24]*ux + M[25]*uy + M[26]*uz + M[27];

    out[tid*3 + 0] = o0;
    out[tid*3 + 1] = o1;
    out[tid*3 + 2] = o2;
}

extern "C" void kernel_launch(void* const* d_in, const int* in_sizes, int n_in,
                              void* d_out, int out_size, void* d_ws, size_t ws_size,
                              hipStream_t stream) {
    const float* coeff    = (const float*)d_in[0];
    const float* affine   = (const float*)d_in[1];
    const float* fix_aff  = (const float*)d_in[2];
    const float* mov_aff  = (const float*)d_in[3];
    float* M = (float*)d_ws;          // 32 floats: fa (16), ma (16)
    float* out = (float*)d_out;

    setup_mats<<<1, 64, 0, stream>>>(affine, fix_aff, mov_aff, M);

    const int total = FD * FD * FD;           // 4,096,000
    const int blocks = total / 256;           // 16000
    spline_field<<<blocks, 256, 0, stream>>>(coeff, M, out);
}